// Round 4
// baseline (556.283 us; speedup 1.0000x reference)
//
#include <hip/hip_runtime.h>

#define SEQ_LEN 96
#define PRED_LEN 16
#define HIDDEN 64
#define FEAT 7
#define BATCH 512
#define TL (SEQ_LEN + PRED_LEN)   // 112-row sliding timeline
#define XSTR 8                    // padded row stride; col 7 == 1.0 (bias lane)

typedef float v2f __attribute__((ext_vector_type(2)));

#define L2E 1.4426950408889634f

// DPP quad ops (pure VALU). Quad = the 4 lanes of one hidden unit.
__device__ __forceinline__ float qp_xor1(float v) {  // [1,0,3,2]
    return __int_as_float(__builtin_amdgcn_mov_dpp(__float_as_int(v), 0xB1, 0xF, 0xF, true));
}
__device__ __forceinline__ float qp_xor2(float v) {  // [2,3,0,1]
    return __int_as_float(__builtin_amdgcn_mov_dpp(__float_as_int(v), 0x4E, 0xF, 0xF, true));
}
__device__ __forceinline__ float qp_rot1(float v) {  // lane q <- lane (q+1)&3 : [1,2,3,0]
    return __int_as_float(__builtin_amdgcn_mov_dpp(__float_as_int(v), 0x39, 0xF, 0xF, true));
}
__device__ __forceinline__ float qp_rot3(float v) {  // lane q <- lane (q+3)&3 : [3,0,1,2]
    return __int_as_float(__builtin_amdgcn_mov_dpp(__float_as_int(v), 0x93, 0xF, 0xF, true));
}

// Forced packed fp32 math. NON-volatile, register-only asm: schedulable,
// DCE-safe (outputs used), but the backend MUST emit pk ops and MUST have
// the weight operands in VGPR pairs (LLVM cannot remat loads in RA, and the
// waves_per_eu(2,2) budget of 256 regs makes spilling pointless).
__device__ __forceinline__ v2f pk_mul(v2f a, v2f b) {
    v2f d;
    asm("v_pk_mul_f32 %0, %1, %2" : "=v"(d) : "v"(a), "v"(b));
    return d;
}
__device__ __forceinline__ void pk_fma(v2f& acc, v2f a, v2f b) {
    asm("v_pk_fma_f32 %0, %1, %2, %0" : "+v"(acc) : "v"(a), "v"(b));
}

// r13 = r11 structure + forced-pk inner loop (no r12 anchors).
//  History of the ~860 cyc/step wall: r7 (AGPR copy tax, 132 VGPR), r11
//  (occupancy-capped remat, 64 VGPR), r12 (anchor-induced scalarization,
//  88 VGPR) -- all landed at ~130-140 real insts/wave-step via different
//  codegen failures. Hand count is ~67 packed insts. This round forces the
//  packing and weight residency at the instruction level instead of fighting
//  allocator heuristics with attributes.
//  Decomposition (r11): thread = (unit u = tid>>2, K-quarter q = tid&3),
//  all 4 gates per lane; 4x h reuse (16KB/block-step LDS); rotation-reduce
//  leaves lane q holding gate q's full preactivation; 3 DPP xors share
//  (i,f,g,o); redundant c-chain per quad; sink writes 2-way bank-free.
//  grid 512 x 256 thr -> 2 staggered blocks/CU, 2 waves/SIMD.
__global__ __launch_bounds__(256)
__attribute__((amdgpu_waves_per_eu(2, 2)))
void lstm_ar_kernel(
    const float* __restrict__ x,     // [B, 96, 7]
    const float* __restrict__ W_ih,  // [256, 7]
    const float* __restrict__ W_hh,  // [256, 64]
    const float* __restrict__ b_ih,  // [256]
    const float* __restrict__ b_hh,  // [256]
    const float* __restrict__ fc_W,  // [7, 64]
    const float* __restrict__ fc_b,  // [7]
    float* __restrict__ out)         // [B, 16, 7]
{
    __shared__ float xs[TL * XSTR];   // sliding timeline, col7 = 1.0
    __shared__ float hb0[HIDDEN];     // h ping-pong
    __shared__ float hb1[HIDDEN];
    __shared__ float hscr[HIDDEN];    // garbage-h sink (never read)
    __shared__ float fcw[FEAT * HIDDEN];
    __shared__ float fcb[FEAT];

    const int tid = threadIdx.x;
    const int b   = blockIdx.x;
    const int u   = tid >> 2;         // hidden unit 0..63
    const int q   = tid & 3;          // K-quarter 0..3, also "own gate" id

    // ---- per-thread weights: 4 gates x K-quarter [16q,16q+16) ----
    // accumulator k holds gate (q+k)&3  (rotated layout for the DPP reduce)
    v2f wh[4][8];
    #pragma unroll
    for (int k = 0; k < 4; ++k) {
        const int gate = (q + k) & 3;
        const float* wr = W_hh + ((gate << 6) + u) * HIDDEN + (q << 4);
        #pragma unroll
        for (int j = 0; j < 8; ++j) wh[k][j] = *(const v2f*)(wr + 2 * j);
    }
    v2f wx[4];                        // x cols [2q, 2q+2); q==3 pairs col6 with bias
    #pragma unroll
    for (int k = 0; k < 4; ++k) {
        const int gate = (q + k) & 3;
        const int row  = (gate << 6) + u;
        const int c0 = (q << 1), c1 = c0 + 1;
        wx[k].x = W_ih[row * FEAT + c0];
        wx[k].y = (c1 < FEAT) ? W_ih[row * FEAT + c1]
                              : (b_ih[row] + b_hh[row]);   // pairs with xs col7==1.0
    }

    // activation constants: lane q activates gate q; gate 2 is tanh
    const float bk  = (q == 2) ? (-2.0f * L2E) : (-L2E);
    const float bm  = (q == 2) ? 2.0f : 1.0f;
    const float bbc = (q == 2) ? -1.0f : 0.0f;

    // h-write pointers: real for q==0; sink slots (u+16q)&63 give every wave a
    // perfect 2-per-bank store pattern
    float* const sink = hscr + ((u + (q << 4)) & 63);
    float* const wa1 = (q == 0) ? (hb1 + u) : sink;
    float* const wa0 = (q == 0) ? (hb0 + u) : sink;

    // per-lane h-read base: K-quarter q => 4 float4s at hb + 16q
    const float4* const h40 = (const float4*)(hb0 + (q << 4));
    const float4* const h41 = (const float4*)(hb1 + (q << 4));
    const float* const xq = xs + (q << 1);   // this lane's 2 x-cols

    // ---- stage timeline / fc / init ----
    for (int i = tid; i < TL * XSTR; i += 256) {
        int r = i >> 3, f = i & 7;
        float v = 1.0f;                                    // col 7 = bias input
        if (f < FEAT) v = (r < SEQ_LEN) ? x[b * SEQ_LEN * FEAT + r * FEAT + f] : 0.0f;
        xs[i] = v;
    }
    for (int i = tid; i < FEAT * HIDDEN; i += 256) fcw[i] = fc_W[i];
    if (tid < FEAT)   fcb[tid] = fc_b[tid];
    if (tid < HIDDEN) hb0[tid] = 0.0f;
    float c = 0.0f;                   // real only in q==0 lanes; bounded garbage elsewhere
    __syncthreads();

    // One step: consumes prefetched x pair, reads h quarter (4x b128), rotation-
    // reduces across the quad, activates own gate, shares via DPP, writes h,
    // prefetches x row `nrow` in the barrier shadow. ONE barrier per step.
    auto step = [&](v2f xv, int nrow, const float4* __restrict__ h4,
                    float* __restrict__ wa) -> v2f {
        v2f A0 = pk_mul(wx[0], xv);   // bias rides in via q==3's wx[k].y * 1.0
        v2f A1 = pk_mul(wx[1], xv);
        v2f A2 = pk_mul(wx[2], xv);
        v2f A3 = pk_mul(wx[3], xv);

        #pragma unroll
        for (int j = 0; j < 4; ++j) {                 // 16 h values, 4x reuse
            float4 hv = h4[j];
            v2f lo; lo.x = hv.x; lo.y = hv.y;
            v2f hi; hi.x = hv.z; hi.y = hv.w;
            pk_fma(A0, wh[0][2*j],   lo);
            pk_fma(A1, wh[1][2*j],   lo);
            pk_fma(A2, wh[2][2*j],   lo);
            pk_fma(A3, wh[3][2*j],   lo);
            pk_fma(A0, wh[0][2*j+1], hi);
            pk_fma(A1, wh[1][2*j+1], hi);
            pk_fma(A2, wh[2][2*j+1], hi);
            pk_fma(A3, wh[3][2*j+1], hi);
        }

        // horizontal, then rotation-reduce: lane q gathers gate q's partials
        // (lane q+d holds gate q at accumulator index (4-d)&3)
        float r0 = A0.x + A0.y;       // own partial of gate q
        float r1 = A1.x + A1.y;       // gate q+1
        float r2 = A2.x + A2.y;       // gate q+2
        float r3 = A3.x + A3.y;       // gate q+3
        float sum = r0 + qp_rot1(r3);
        sum += qp_xor2(r2);           // rot2 == xor2
        sum += qp_rot3(r1);

        // activate own gate (q==2 -> tanh, else sigmoid)
        float e   = __builtin_amdgcn_exp2f(sum * bk);
        float rc  = __builtin_amdgcn_rcpf(1.0f + e);
        float a   = fmaf(bm, rc, bbc);

        // quad share: lane 0 sees a=i, p1=f, p2=g, p3=o (zero selects)
        float p1 = qp_xor1(a);
        float p2 = qp_xor2(a);
        float p3 = qp_xor2(p1);

        c = fmaf(p1, c, a * p2);                      // c = f*c + i*g
        float e2 = __builtin_amdgcn_exp2f(c * (-2.0f * L2E));
        float rr = __builtin_amdgcn_rcpf(1.0f + e2);
        float th = fmaf(2.0f, rr, -1.0f);             // tanh(c)
        *wa = p3 * th;                                // h = o*tanh(c); q!=0 -> sink

        // prefetch next x pair in the barrier shadow
        v2f nxt = *(const v2f*)(xq + nrow * XSTR);
        __syncthreads();              // the ONLY barrier per step
        return nxt;
    };

    for (int k = 0; k < PRED_LEN; ++k) {
        v2f cur = *(const v2f*)(xq + k * XSTR);       // row k (t=0)
        for (int t = 0; t < SEQ_LEN; t += 2) {
            cur = step(cur, k + t + 1, h40, wa1);
            cur = step(cur, k + t + 2, h41, wa0);     // t=94: prefetch row k+96 (stale, discarded)
        }
        // after 96 steps the latest h is in hb0

        // ---- prediction head: lanes 0..6 of wave 0 ----
        if (tid < FEAT) {
            float p0 = fcb[tid], p1 = 0.0f, p2 = 0.0f, p3 = 0.0f;
            const float4* hh = (const float4*)hb0;
            #pragma unroll
            for (int j = 0; j < 16; ++j) {
                float4 hv = hh[j];
                p0 = fmaf(fcw[tid * HIDDEN + 4 * j + 0], hv.x, p0);
                p1 = fmaf(fcw[tid * HIDDEN + 4 * j + 1], hv.y, p1);
                p2 = fmaf(fcw[tid * HIDDEN + 4 * j + 2], hv.z, p2);
                p3 = fmaf(fcw[tid * HIDDEN + 4 * j + 3], hv.w, p3);
            }
            float pred = (p0 + p1) + (p2 + p3);
            out[(b * PRED_LEN + k) * FEAT + tid] = pred;
            xs[(SEQ_LEN + k) * XSTR + tid] = pred;    // append; col7 stays 1.0
        }
        __syncthreads();
    }
}

extern "C" void kernel_launch(void* const* d_in, const int* in_sizes, int n_in,
                              void* d_out, int out_size, void* d_ws, size_t ws_size,
                              hipStream_t stream) {
    const float* x    = (const float*)d_in[0];
    const float* W_ih = (const float*)d_in[1];
    const float* W_hh = (const float*)d_in[2];
    const float* b_ih = (const float*)d_in[3];
    const float* b_hh = (const float*)d_in[4];
    const float* fc_W = (const float*)d_in[5];
    const float* fc_b = (const float*)d_in[6];
    float* out = (float*)d_out;

    lstm_ar_kernel<<<BATCH, 256, 0, stream>>>(x, W_ih, W_hh, b_ih, b_hh, fc_W, fc_b, out);
}